// Round 6
// baseline (11587.766 us; speedup 1.0000x reference)
//
#include <hip/hip_runtime.h>
#include <math.h>

#define FIN 500
#define NHID 64
#define NCLS 40
#define NLAYERS 8
#define PTILE 16384              // edges per partition block
#define RSHIFT 12                // 4096 rows per fine bucket
#define RROWS 4096
#define NCHUNK 6                 // col chunks of 16667 cols = 2.13 MB of h < 4 MB L2/XCD
#define CDIV 16667u

typedef _Float16 half8 __attribute__((ext_vector_type(8)));
typedef float f32x4 __attribute__((ext_vector_type(4)));

__device__ __forceinline__ int col_chunk(int c) {
  int ch = (int)((unsigned)c / CDIV);
  return (ch > NCHUNK - 1) ? (NCHUNK - 1) : ch;
}

// ---------------- prep: transpose weights to fp16 [c][k] ----------------
__global__ __launch_bounds__(256) void k_prep(
    const float* __restrict__ Wi, const float* __restrict__ Wc,
    _Float16* __restrict__ WtIn, _Float16* __restrict__ WcT) {
  const int t = blockIdx.x * 256 + threadIdx.x;
  const int stride = gridDim.x * 256;
  for (int i = t; i < 64 * 512; i += stride) {
    int c = i >> 9, k = i & 511;
    WtIn[i] = (k < FIN) ? (_Float16)Wi[k * 64 + c] : (_Float16)0.f;
  }
  for (int i = t; i < NLAYERS * 64 * 64; i += stride) {
    int l = i >> 12, rem = i & 4095, c = rem >> 6, k = rem & 63;
    WcT[i] = (_Float16)Wc[l * 4096 + k * 64 + c];
  }
}

// ---------------- h0 = relu(x @ W_in + b_in) -> fp16, MFMA ----------------
// v3: LDS-staged, fully coalesced loads (x: 8 thr/row = 128B segments).
// xs/ws stride 40 halfs (80 B): 16B-aligned b128 frag reads, 2-way banks (free).
__global__ __launch_bounds__(256, 8) void k_gemm_in(
    const float* __restrict__ x, const _Float16* __restrict__ Wt,
    const float* __restrict__ b, _Float16* __restrict__ h0, int n) {
  __shared__ _Float16 xs[64 * 40];
  __shared__ _Float16 ws[64 * 40];
  const int tid = threadIdx.x;
  const int lane = tid & 63;
  const int wv = tid >> 6;
  const int row0 = blockIdx.x * 64;
  // x staging: thread covers rows rA and rA+32 at k-offset kx (float4 each)
  const int rA = tid >> 3, kx = (tid & 7) * 4;
  int g0r = row0 + rA;        if (g0r >= n) g0r = n - 1;
  int g1r = row0 + 32 + rA;   if (g1r >= n) g1r = n - 1;
  const float* xr0 = x + (size_t)g0r * FIN;
  const float* xr1 = x + (size_t)g1r * FIN;
  // W staging: thread covers col cW at k-offset kw (half8)
  const int cW = tid >> 2, kw = (tid & 3) * 8;
  // frag indices
  const int al = lane & 15;
  const int kq = lane >> 4;
  f32x4 acc[4];
#pragma unroll
  for (int ct = 0; ct < 4; ++ct) acc[ct] = (f32x4){0.f, 0.f, 0.f, 0.f};

  float4 q0, q1;
  half8 wq;
  {
    const int gk = kx;                      // tile 0 always in range
    q0 = *reinterpret_cast<const float4*>(xr0 + gk);
    q1 = *reinterpret_cast<const float4*>(xr1 + gk);
    wq = *reinterpret_cast<const half8*>(Wt + (size_t)cW * 512 + kw);
  }
  for (int t = 0; t < 16; ++t) {
    __syncthreads();                        // prior tile's frag reads done
    {
      half8 hx;
      hx[0] = (_Float16)q0.x; hx[1] = (_Float16)q0.y;
      hx[2] = (_Float16)q0.z; hx[3] = (_Float16)q0.w;
      *reinterpret_cast<half8*>(&xs[rA * 40 + kx]) =
          (half8){hx[0], hx[1], hx[2], hx[3], hx[0], hx[0], hx[0], hx[0]};
      // store as two half4 writes (8B) to keep alignment simple
      _Float16* px0 = &xs[rA * 40 + kx];
      px0[0] = (_Float16)q0.x; px0[1] = (_Float16)q0.y;
      px0[2] = (_Float16)q0.z; px0[3] = (_Float16)q0.w;
      _Float16* px1 = &xs[(32 + rA) * 40 + kx];
      px1[0] = (_Float16)q1.x; px1[1] = (_Float16)q1.y;
      px1[2] = (_Float16)q1.z; px1[3] = (_Float16)q1.w;
      *reinterpret_cast<half8*>(&ws[cW * 40 + kw]) = wq;
    }
    if (t < 15) {
      const int gk = (t + 1) * 32;
      const int gx = gk + kx;
      if (gx + 3 < FIN) {
        q0 = *reinterpret_cast<const float4*>(xr0 + gx);
        q1 = *reinterpret_cast<const float4*>(xr1 + gx);
      } else {
        q0 = (float4){0.f, 0.f, 0.f, 0.f};
        q1 = (float4){0.f, 0.f, 0.f, 0.f};
      }
      wq = *reinterpret_cast<const half8*>(Wt + (size_t)cW * 512 + gk + kw);
    }
    __syncthreads();
    const half8 a = *reinterpret_cast<const half8*>(&xs[(wv * 16 + al) * 40 + kq * 8]);
#pragma unroll
    for (int ct = 0; ct < 4; ++ct) {
      const half8 bf = *reinterpret_cast<const half8*>(&ws[(ct * 16 + al) * 40 + kq * 8]);
      acc[ct] = __builtin_amdgcn_mfma_f32_16x16x32_f16(a, bf, acc[ct], 0, 0, 0);
    }
  }
  const int orow = row0 + wv * 16 + (lane >> 4) * 4;
#pragma unroll
  for (int ct = 0; ct < 4; ++ct) {
    const int c = ct * 16 + al;
    const float bb = b[c];
#pragma unroll
    for (int i = 0; i < 4; ++i) {
      const int rr = orow + i;
      if (rr < n)
        h0[(size_t)rr * NHID + c] = (_Float16)fmaxf(acc[ct][i] + bb, 0.f);
    }
  }
}

// ---------------- coarse histogram: (chunk, row>>12) buckets ----------------
__global__ __launch_bounds__(256) void k_chist(
    const int* __restrict__ row, const int* __restrict__ col,
    int* __restrict__ ccnt, int e_total, int rh) {
  __shared__ int hist[256];
  const int tid = threadIdx.x;
  hist[tid] = 0;
  __syncthreads();
  const int e0 = blockIdx.x * PTILE;
  for (int t = 0; t < PTILE / 256; ++t) {
    int e = e0 + t * 256 + tid;
    if (e < e_total)
      atomicAdd(&hist[col_chunk(col[e]) * rh + (row[e] >> RSHIFT)], 1);
  }
  __syncthreads();
  if (hist[tid]) atomicAdd(&ccnt[tid], hist[tid]);
}

// ---------------- scan coarse counts -> cbase, bcur ----------------
__global__ __launch_bounds__(256) void k_cscan(
    const int* __restrict__ ccnt, int* __restrict__ cbase,
    int* __restrict__ bcur, int nbC) {
  __shared__ int sh[257];
  const int t = threadIdx.x;
  sh[t] = (t < nbC) ? ccnt[t] : 0;
  __syncthreads();
  if (t == 0) {
    int run = 0;
    for (int i = 0; i < 256; ++i) { int v = sh[i]; sh[i] = run; run += v; }
    sh[256] = run;
  }
  __syncthreads();
  if (t <= nbC) cbase[t] = sh[t];
  if (t < nbC) bcur[t] = sh[t];
}

// ---------------- pass 1: block-local coarse partition ----------------
__global__ __launch_bounds__(256) void k_part2(
    const int* __restrict__ row, const int* __restrict__ col,
    const float* __restrict__ w, int* __restrict__ bcurG,
    int2* __restrict__ staged, int e_total, int nbC, int rh) {
  __shared__ int hist[256];
  __shared__ int cur[256];
  const int tid = threadIdx.x;
  const int e0 = blockIdx.x * PTILE;
  if (tid < nbC) hist[tid] = 0;
  __syncthreads();
  for (int t = 0; t < PTILE / 256; ++t) {
    int e = e0 + t * 256 + tid;
    if (e < e_total)
      atomicAdd(&hist[col_chunk(col[e]) * rh + (row[e] >> RSHIFT)], 1);
  }
  __syncthreads();
  if (tid < nbC) {
    int h = hist[tid];
    cur[tid] = h ? atomicAdd(&bcurG[tid], h) : 0;
  }
  __syncthreads();
  for (int t = 0; t < PTILE / 256; ++t) {
    int e = e0 + t * 256 + tid;
    if (e < e_total) {
      int r = row[e], c = col[e];
      int pos = atomicAdd(&cur[col_chunk(c) * rh + (r >> RSHIFT)], 1);
      staged[pos] = make_int2(((r & (RROWS - 1)) << 17) | c, __float_as_int(w[e]));
    }
  }
}

// ------- pass 2: per-bucket 4096-row hist + scan -> ptr2; place edges -------
__global__ __launch_bounds__(256) void k_rebin4(
    const int* __restrict__ cbase, const int2* __restrict__ staged,
    int2* __restrict__ sorted, int* __restrict__ ptr2, int rh) {
  __shared__ int rcnt[RROWS];
  __shared__ int cur[RROWS];
  __shared__ int wsum[4];
  const int tid = threadIdx.x;
  const int k = blockIdx.x / rh;
  const int rhigh = blockIdx.x - k * rh;
  const int bstart = cbase[blockIdx.x], bend = cbase[blockIdx.x + 1];
  for (int i = tid; i < RROWS; i += 256) rcnt[i] = 0;
  __syncthreads();
  for (int i = bstart + tid; i < bend; i += 256)
    atomicAdd(&rcnt[staged[i].x >> 17], 1);
  __syncthreads();
  const int base = tid * 16;
  int s = 0;
#pragma unroll
  for (int j = 0; j < 16; ++j) s += rcnt[base + j];
  const int lane = tid & 63, wid = tid >> 6;
  int incl = s;
#pragma unroll
  for (int off = 1; off < 64; off <<= 1) {
    int u = __shfl_up(incl, off, 64);
    if (lane >= off) incl += u;
  }
  if (lane == 63) wsum[wid] = incl;
  __syncthreads();
  int woff = 0;
  for (int i = 0; i < wid; ++i) woff += wsum[i];
  int run = bstart + (incl - s) + woff;
  int* p2 = ptr2 + (size_t)k * (rh << RSHIFT) + (rhigh << RSHIFT);
#pragma unroll
  for (int j = 0; j < 16; ++j) {
    int c = rcnt[base + j];
    p2[base + j] = run;
    cur[base + j] = run;
    run += c;
  }
  __syncthreads();
  for (int i = bstart + tid; i < bend; i += 256) {
    int2 e = staged[i];
    int pos = atomicAdd(&cur[e.x >> 17], 1);
    sorted[pos] = e;
  }
}

// ---- fused layer v4: chunk-phased SpMM with BATCHED descriptor/gather loads.
// Per wave per chunk: contiguous 16-row edge range split into 8 contiguous
// slot sub-ranges.  Inner loop: 4 desc loads (1 wait) -> 4 gathers (1 wait)
// -> 32 ds_add_f32 into wave-private LDS S tile.  2 round-trips per 4 edges
// (was 2 per edge).  Branch-free: invalid lanes clamp index + zero weight.
__global__ __launch_bounds__(256, 8) void k_fused(
    const int* __restrict__ ptr2, const int2* __restrict__ sorted,
    const _Float16* __restrict__ hin, const _Float16* __restrict__ h0,
    const _Float16* __restrict__ Wt, _Float16* __restrict__ hout,
    float beta, int n, int s2) {
  __shared__ float S[64 * 66];      // stride 66: <=2-way LDS banks (free)
  const int tid = threadIdx.x;
  const int lane = tid & 63;
  const int wid = tid >> 6;
  const int rbase = blockIdx.x * 64 + wid * 16;
  const int fl = lane & 7;          // feature group -> feats fl*8..fl*8+7
  const int sl = lane >> 3;         // slot -> contiguous edge sub-range
  // zero own S rows (wave-private; in-order LDS per wave)
  for (int i = lane; i < 16 * 66; i += 64) S[wid * 16 * 66 + i] = 0.f;
  const _Float16* hf = hin + fl * 8;
  float* Srow = S + wid * 16 * 66 + fl * 8;
  for (int k = 0; k < NCHUNK; ++k) {
    const int* p2 = ptr2 + (size_t)k * s2;
    const int A = p2[rbase];
    const int len = p2[rbase + 16] - A;
    if (len <= 0) continue;
    const int last = A + len - 1;
    const int start = A + ((len * sl) >> 3);
    const int end = A + ((len * (sl + 1)) >> 3);
    const int nt = (len + 31) >> 5;          // uniform across wave
    int e = start;
    for (int it = 0; it < nt; ++it, e += 4) {
      const int e0 = e, e1 = e + 1, e2 = e + 2, e3 = e + 3;
      const int2 d0 = sorted[e0 < end ? e0 : last];
      const int2 d1 = sorted[e1 < end ? e1 : last];
      const int2 d2 = sorted[e2 < end ? e2 : last];
      const int2 d3 = sorted[e3 < end ? e3 : last];
      const half8 g0 = *reinterpret_cast<const half8*>(hf + (size_t)(d0.x & 0x1FFFF) * NHID);
      const half8 g1 = *reinterpret_cast<const half8*>(hf + (size_t)(d1.x & 0x1FFFF) * NHID);
      const half8 g2 = *reinterpret_cast<const half8*>(hf + (size_t)(d2.x & 0x1FFFF) * NHID);
      const half8 g3 = *reinterpret_cast<const half8*>(hf + (size_t)(d3.x & 0x1FFFF) * NHID);
      const float w0 = (e0 < end) ? __int_as_float(d0.y) : 0.f;
      const float w1 = (e1 < end) ? __int_as_float(d1.y) : 0.f;
      const float w2 = (e2 < end) ? __int_as_float(d2.y) : 0.f;
      const float w3 = (e3 < end) ? __int_as_float(d3.y) : 0.f;
      const int r0 = ((d0.x >> 17) & 15) * 66;
      const int r1 = ((d1.x >> 17) & 15) * 66;
      const int r2 = ((d2.x >> 17) & 15) * 66;
      const int r3 = ((d3.x >> 17) & 15) * 66;
#pragma unroll
      for (int j = 0; j < 8; ++j) atomicAdd(&Srow[r0 + j], w0 * (float)g0[j]);
#pragma unroll
      for (int j = 0; j < 8; ++j) atomicAdd(&Srow[r1 + j], w1 * (float)g1[j]);
#pragma unroll
      for (int j = 0; j < 8; ++j) atomicAdd(&Srow[r2 + j], w2 * (float)g2[j]);
#pragma unroll
      for (int j = 0; j < 8; ++j) atomicAdd(&Srow[r3 + j], w3 * (float)g3[j]);
    }
  }
  __syncthreads();                           // drain ds_adds before reads
  // blend: S = 0.9*S + 0.1*h0 (wave's own rows)
  for (int rr = 0; rr < 16; ++rr) {
    const int r = rbase + rr;
    if (r >= n) break;
    float* sp = &S[(wid * 16 + rr) * 66 + lane];
    *sp = 0.9f * *sp + 0.1f * (float)h0[(size_t)r * NHID + lane];
  }
  __syncthreads();
  // MFMA: wave wid -> rows [rbase, rbase+16) x 64 cols; a-frags from own S rows.
  const int al = lane & 15;
  const int kg = (lane >> 4) * 8;
  const float* sa = &S[(wid * 16 + al) * 66 + kg];
  half8 a0, a1;
#pragma unroll
  for (int j = 0; j < 8; ++j) a0[j] = (_Float16)sa[j];
#pragma unroll
  for (int j = 0; j < 8; ++j) a1[j] = (_Float16)sa[32 + j];
  f32x4 acc[4];
#pragma unroll
  for (int ct = 0; ct < 4; ++ct) acc[ct] = (f32x4){0.f, 0.f, 0.f, 0.f};
#pragma unroll
  for (int ct = 0; ct < 4; ++ct) {
    const int c = ct * 16 + al;
    const half8 b0 = *reinterpret_cast<const half8*>(Wt + c * NHID + kg);
    const half8 b1 = *reinterpret_cast<const half8*>(Wt + c * NHID + 32 + kg);
    acc[ct] = __builtin_amdgcn_mfma_f32_16x16x32_f16(a0, b0, acc[ct], 0, 0, 0);
    acc[ct] = __builtin_amdgcn_mfma_f32_16x16x32_f16(a1, b1, acc[ct], 0, 0, 0);
  }
  const float g = 1.f - beta;
  const int ri = (lane >> 4) * 4;
#pragma unroll
  for (int ct = 0; ct < 4; ++ct) {
    const int c = ct * 16 + al;
#pragma unroll
    for (int i = 0; i < 4; ++i) {
      const int r = rbase + ri + i;
      if (r < n) {
        const float sv = S[(wid * 16 + ri + i) * 66 + c];
        hout[(size_t)r * NHID + c] =
            (_Float16)fmaxf(beta * acc[ct][i] + g * sv, 0.f);
      }
    }
  }
}

// ---------------- out = log_softmax(h @ W_out + b_out), persistent ----------------
__global__ __launch_bounds__(256) void k_out(
    const _Float16* __restrict__ h, const float* __restrict__ Wo,
    const float* __restrict__ bo, float* __restrict__ out, int n, int wstride) {
  const int lane = threadIdx.x & 63;
  const int j = (lane < NCLS) ? lane : (NCLS - 1);
  for (int r = blockIdx.x * 4 + (threadIdx.x >> 6); r < n; r += wstride) {
    const float hv = (float)h[(size_t)r * NHID + lane];
    float acc = bo[j];
#pragma unroll 16
    for (int k = 0; k < NHID; ++k) {
      float hk = __shfl(hv, k, 64);
      acc += hk * Wo[k * NCLS + j];
    }
    float v = (lane < NCLS) ? acc : -INFINITY;
    float m = v;
#pragma unroll
    for (int off = 32; off; off >>= 1) m = fmaxf(m, __shfl_xor(m, off, 64));
    float e = (lane < NCLS) ? expf(acc - m) : 0.f;
    float s = e;
#pragma unroll
    for (int off = 32; off; off >>= 1) s += __shfl_xor(s, off, 64);
    if (lane < NCLS) out[(size_t)r * NCLS + lane] = acc - m - logf(s);
  }
}

extern "C" void kernel_launch(void* const* d_in, const int* in_sizes, int n_in,
                              void* d_out, int out_size, void* d_ws, size_t ws_size,
                              hipStream_t stream) {
  const float* x  = (const float*)d_in[0];
  const int* row  = (const int*)d_in[1];
  const int* col  = (const int*)d_in[2];
  const float* ew = (const float*)d_in[3];
  const float* Wi = (const float*)d_in[4];
  const float* bi = (const float*)d_in[5];
  const float* Wc = (const float*)d_in[6];
  const float* Wo = (const float*)d_in[7];
  const float* bo = (const float*)d_in[8];
  float* out = (float*)d_out;

  const int n = in_sizes[0] / FIN;   // 100000
  const int E = in_sizes[1];         // 3200000

  const int rh = (n + RROWS - 1) >> RSHIFT;       // 25
  const int s2 = rh << RSHIFT;                    // 102400 (ptr2 stride per chunk)
  const int nbC2 = NCHUNK * rh;                   // 150

  // workspace layout (~95 MB)
  _Float16* h0h = (_Float16*)d_ws;                      // n*64 f16
  _Float16* hhA = h0h + (size_t)n * NHID;               // n*64 f16
  _Float16* hhB = hhA + (size_t)n * NHID;               // n*64 f16
  int2* staged  = (int2*)(hhB + (size_t)n * NHID);      // E int2
  int2* sorted  = staged + E;                           // E int2
  int*  ptr2    = (int*)(sorted + E);                   // NCHUNK*s2 + 1
  int*  ccnt    = ptr2 + (size_t)NCHUNK * s2 + 1;       // 256
  int*  cbase   = ccnt + 256;                           // 257
  int*  bcur    = cbase + 257;                          // 256
  _Float16* WtIn = (_Float16*)(((uintptr_t)(bcur + 256) + 63) & ~(uintptr_t)63);
  _Float16* WcT  = WtIn + 64 * 512;                     // 8*64*64 f16

  const int nPB = (E + PTILE - 1) / PTILE;              // 196
  const int nBF = (n + 63) / 64;                        // 1563
  dim3 blk(256);

  // ---- CSR build keyed by (col-chunk, row) ----
  hipMemsetAsync(ccnt, 0, 256 * sizeof(int), stream);
  k_chist<<<dim3(nPB), blk, 0, stream>>>(row, col, ccnt, E, rh);
  k_cscan<<<dim3(1), blk, 0, stream>>>(ccnt, cbase, bcur, nbC2);
  k_part2<<<dim3(nPB), blk, 0, stream>>>(row, col, ew, bcur, staged, E, nbC2, rh);
  k_rebin4<<<dim3(nbC2), blk, 0, stream>>>(cbase, staged, sorted, ptr2, rh);

  // ---- fp16 weight transposes ----
  k_prep<<<dim3(64), blk, 0, stream>>>(Wi, Wc, WtIn, WcT);

  // ---- dense input projection (MFMA, LDS-staged coalesced) ----
  k_gemm_in<<<dim3(nBF), blk, 0, stream>>>(x, WtIn, bi, h0h, n);

  // ---- 8 GCNII layers: fused chunk-phased SpMM + blend + GEMM + relu ----
  const _Float16* hin = h0h;
  for (int l = 0; l < NLAYERS; ++l) {
    _Float16* hout = (l & 1) ? hhB : hhA;
    float beta = logf(0.5f / (float)(l + 1) + 1.f);
    k_fused<<<dim3(nBF), blk, 0, stream>>>(
        ptr2, sorted, hin, h0h, WcT + (size_t)l * NHID * NHID, hout, beta, n, s2);
    hin = hout;
  }
  const int outBlocks = 2048;
  k_out<<<dim3(outBlocks), blk, 0, stream>>>(hin, Wo, bo, out, n, outBlocks * 4);
}